// Round 3
// baseline (277.827 us; speedup 1.0000x reference)
//
#include <hip/hip_runtime.h>
#include <hip/hip_bf16.h>
#include <stdint.h>

typedef __bf16 bf16;
typedef __bf16 bf16x8 __attribute__((ext_vector_type(8)));
typedef float f32x4 __attribute__((ext_vector_type(4)));

#define BATCH 4
#define SEQ   2048
#define DIM   1024
#define NH    16
#define HD    64

// Q projection pre-scaled by (1/sqrt(HD)) * log2(e): softmax runs in exp2 domain.
#define QSCALE 0.18033688011112042f  // 0.125 * 1.4426950408889634

#define MFMA(a, b, c) __builtin_amdgcn_mfma_f32_16x16x32_bf16((a), (b), (c), 0, 0, 0)

// global -> LDS direct copy, 16B per lane. LDS dest is wave-uniform base+lane*16.
#define GLOAD16(gsrc, ldst)                                                        \
  __builtin_amdgcn_global_load_lds(                                                \
      (__attribute__((address_space(1))) unsigned int*)(void*)(gsrc),              \
      (__attribute__((address_space(3))) unsigned int*)(ldst), 16, 0, 0)

static __device__ __forceinline__ float fast_exp2(float x) {
#if __has_builtin(__builtin_amdgcn_exp2f)
  return __builtin_amdgcn_exp2f(x);
#else
  return exp2f(x);
#endif
}

// ---------------------------------------------------------------------------
// Weight conversion: f32 -> bf16, 4 tensors of DIM*DIM each.
// ---------------------------------------------------------------------------
__global__ __launch_bounds__(256) void cvt_w_kernel(
    const float* __restrict__ w0, const float* __restrict__ w1,
    const float* __restrict__ w2, const float* __restrict__ w3,
    bf16* __restrict__ o0, bf16* __restrict__ o1,
    bf16* __restrict__ o2, bf16* __restrict__ o3) {
  const float* s;
  bf16* d;
  switch (blockIdx.y) {
    case 0: s = w0; d = o0; break;
    case 1: s = w1; d = o1; break;
    case 2: s = w2; d = o2; break;
    default: s = w3; d = o3; break;
  }
  const int i = (blockIdx.x * 256 + threadIdx.x) * 4;
  const float4 v = *(const float4*)(s + i);
  ushort4 o;
  o.x = __builtin_bit_cast(unsigned short, (bf16)v.x);
  o.y = __builtin_bit_cast(unsigned short, (bf16)v.y);
  o.z = __builtin_bit_cast(unsigned short, (bf16)v.z);
  o.w = __builtin_bit_cast(unsigned short, (bf16)v.w);
  *(ushort4*)((unsigned short*)d + i) = o;
}

// ---------------------------------------------------------------------------
// Projection GEMM: C[m,n] = sum_k A[m,k] * W[n,k] + bias[n]   (nn.Linear)
// A: f32, reg-staged (issue-early/write-late) + converted to bf16 LDS.
// W: bf16, staged via global_load_lds.
// Tile 128x128, BK=64, 128B LDS rows with (row&7)<<4 XOR swizzle,
// double-buffered, ONE barrier per K-step, XCD-chunked block swizzle.
// z=0: out = bf16(C * QSCALE)   (Q) | z=1: bf16(C) (K) | z=2: Vt transposed.
// ---------------------------------------------------------------------------
struct ProjArgs {
  const float* A[3];
  const bf16*  W[3];
  const float* bias[3];
  bf16*        out[3];
};

__global__ __launch_bounds__(256, 2) void proj_gemm(ProjArgs p) {
  const int z = blockIdx.z;
  const float* __restrict__ A    = p.A[z];
  const bf16*  __restrict__ W    = p.W[z];
  const float* __restrict__ bias = p.bias[z];
  bf16*        __restrict__ out  = p.out[z];

  __shared__ bf16 Ab[2][128 * 64];  // [row 128][k 64] bf16, 128B rows, swizzled
  __shared__ bf16 Bb[2][128 * 64];

  const int tid  = threadIdx.x;
  const int wave = tid >> 6, lane = tid & 63;
  const int r = lane & 15, g = lane >> 4;

  // XCD-chunked swizzle: 512 blocks -> each XCD gets 64 contiguous (8m x 8n)
  const int wg = blockIdx.x;
  const int sw = ((wg & 7) << 6) | (wg >> 3);
  const int m0 = (sw >> 3) * 128, n0 = (sw & 7) * 128;
  const int wm = (wave >> 1) * 64, wn = (wave & 1) * 64;

  f32x4 acc[4][4] = {};

  // B staging via GLOAD16: wave covers rows [wave*32, wave*32+32)
  const int srr = lane >> 3;        // sub-row within 8-row group
  const int scb = (lane & 7) * 16;  // byte col
  const int swz = srr << 4;         // == (row&7)<<4 for staged rows

#define STAGE_B(buf, k0)                                                            \
  do {                                                                              \
    _Pragma("unroll") for (int i_ = 0; i_ < 4; ++i_) {                              \
      const int row_ = wave * 32 + i_ * 8 + srr;                                    \
      const char* src_ =                                                            \
          (const char*)(W + (size_t)(n0 + row_) * DIM + (k0)) + (scb ^ swz);        \
      GLOAD16(src_, (char*)&Bb[buf][0] + (wave * 32 + i_ * 8) * 128);               \
    }                                                                               \
  } while (0)

  // A staging: lane owns half a row (arow = tid/2, ah = 64B-half)
  const int arow = tid >> 1;
  const int ah   = tid & 1;
  const float* aptr = A + (size_t)(m0 + arow) * DIM + ah * 32;
  const int aswz = (arow & 7) << 4;

#define LOAD_A(av, k0)                                                              \
  _Pragma("unroll") for (int j_ = 0; j_ < 8; ++j_)                                  \
      av[j_] = *(const float4*)(aptr + (k0) + j_ * 4)

#define WRITE_A(buf, av)                                                            \
  do {                                                                              \
    char* adst_ = (char*)&Ab[buf][0] + arow * 128;                                  \
    _Pragma("unroll") for (int c_ = 0; c_ < 4; ++c_) {                              \
      bf16x8 pk_;                                                                   \
      pk_[0] = (bf16)av[2 * c_].x;     pk_[1] = (bf16)av[2 * c_].y;                 \
      pk_[2] = (bf16)av[2 * c_].z;     pk_[3] = (bf16)av[2 * c_].w;                 \
      pk_[4] = (bf16)av[2 * c_ + 1].x; pk_[5] = (bf16)av[2 * c_ + 1].y;             \
      pk_[6] = (bf16)av[2 * c_ + 1].z; pk_[7] = (bf16)av[2 * c_ + 1].w;             \
      *(bf16x8*)(adst_ + ((ah * 64 + c_ * 16) ^ aswz)) = pk_;                       \
    }                                                                               \
  } while (0)

  // prologue: fill buffer 0
  STAGE_B(0, 0);
  {
    float4 av[8];
    LOAD_A(av, 0);
    WRITE_A(0, av);
  }
  __syncthreads();

  const int NK = DIM / 64;
  for (int it = 0; it < NK; ++it) {
    const int cur = it & 1;
    float4 av[8];
    if (it + 1 < NK) {
      STAGE_B(cur ^ 1, (it + 1) * 64);   // async, no VGPR
      LOAD_A(av, (it + 1) * 64);         // issue early (hides under MFMA)
    }

#pragma unroll
    for (int ks = 0; ks < 2; ++ks) {
      bf16x8 af[4], bfr[4];
#pragma unroll
      for (int mt = 0; mt < 4; ++mt) {
        const int mr = wm + mt * 16 + r;
        af[mt] = *(bf16x8*)((char*)&Ab[cur][0] + mr * 128 +
                            ((ks * 64 + g * 16) ^ ((mr & 7) << 4)));
      }
#pragma unroll
      for (int nt = 0; nt < 4; ++nt) {
        const int nr = wn + nt * 16 + r;
        bfr[nt] = *(bf16x8*)((char*)&Bb[cur][0] + nr * 128 +
                             ((ks * 64 + g * 16) ^ ((nr & 7) << 4)));
      }
#pragma unroll
      for (int mt = 0; mt < 4; ++mt)
#pragma unroll
        for (int nt = 0; nt < 4; ++nt)
          acc[mt][nt] = MFMA(af[mt], bfr[nt], acc[mt][nt]);
    }

    if (it + 1 < NK) WRITE_A(cur ^ 1, av);  // write late
    __syncthreads();
  }
#undef STAGE_B
#undef LOAD_A
#undef WRITE_A

  // --- epilogue ---  C/D layout: row = g*4 + i, col = r (per 16x16 tile)
  if (z == 2) {
#pragma unroll
    for (int nt = 0; nt < 4; ++nt) {
      const int n = n0 + wn + nt * 16 + r;
      const float bn = bias[n];
#pragma unroll
      for (int mt = 0; mt < 4; ++mt) {
        const int m = m0 + wm + mt * 16 + g * 4;
        const int b = m >> 11, t = m & 2047;
        ushort4 pk;
        pk.x = __builtin_bit_cast(unsigned short, (bf16)(acc[mt][nt][0] + bn));
        pk.y = __builtin_bit_cast(unsigned short, (bf16)(acc[mt][nt][1] + bn));
        pk.z = __builtin_bit_cast(unsigned short, (bf16)(acc[mt][nt][2] + bn));
        pk.w = __builtin_bit_cast(unsigned short, (bf16)(acc[mt][nt][3] + bn));
        *(ushort4*)((unsigned short*)out + (((size_t)(b * DIM + n)) << 11) + t) = pk;
      }
    }
  } else {
    const float scale = (z == 0) ? QSCALE : 1.0f;
#pragma unroll
    for (int mt = 0; mt < 4; ++mt)
#pragma unroll
      for (int nt = 0; nt < 4; ++nt) {
        const int n = n0 + wn + nt * 16 + r;
        const float bn = bias[n];
#pragma unroll
        for (int i = 0; i < 4; ++i) {
          const int m = m0 + wm + mt * 16 + g * 4 + i;
          out[(size_t)m * DIM + n] = (bf16)((acc[mt][nt][i] + bn) * scale);
        }
      }
  }
}

// ---------------------------------------------------------------------------
// Fused attention, swapped-QK^T structure (unchanged from R2 — verified).
// ---------------------------------------------------------------------------
__global__ __launch_bounds__(256, 3) void attn_kernel(
    const bf16* __restrict__ Q, const bf16* __restrict__ K,
    const bf16* __restrict__ Vt, bf16* __restrict__ ctx) {
  __shared__ bf16 Kb[2][64 * 64];   // [kv 64][d 64], 128B rows, XOR-swizzled
  __shared__ bf16 Vb[2][64 * 64];   // [d 64][kv 64], 128B rows, XOR-swizzled
  __shared__ bf16 Pb[4][32 * 64];   // per-wave P[q 32][kv 64], XOR-swizzled

  const int tid  = threadIdx.x;
  const int wave = tid >> 6, lane = tid & 63;
  const int r = lane & 15, g = lane >> 4;
  const int bh = blockIdx.y;
  const int b = bh >> 4, h = bh & 15;
  const int q0 = blockIdx.x * 128 + wave * 32;

  bf16x8 qf[2][2];
  {
    const bf16* qp = Q + ((size_t)(b * SEQ + q0 + r) * DIM + h * HD);
#pragma unroll
    for (int qt = 0; qt < 2; ++qt)
#pragma unroll
      for (int ks = 0; ks < 2; ++ks)
        qf[qt][ks] = *(const bf16x8*)(qp + (size_t)qt * 16 * DIM + ks * 32 + g * 8);
  }

  f32x4 accO[2][4] = {};
  float m_i[2] = {-3e38f, -3e38f};
  float l_i[2] = {0.f, 0.f};

  const bf16* Kbase = K + (size_t)(b * SEQ) * DIM + h * HD;
  const bf16* Vbase = Vt + (size_t)(b * DIM + h * HD) * SEQ;

  const int srr = lane >> 3;
  const int scb = (lane & 7) * 16;
  const int swz = srr << 4;

#define STAGE(buf, kv0)                                                             \
  do {                                                                              \
    _Pragma("unroll") for (int i_ = 0; i_ < 2; ++i_) {                              \
      const int row_ = wave * 16 + i_ * 8 + srr;                                    \
      const char* ks_ =                                                             \
          (const char*)(Kbase + (size_t)((kv0) + row_) * DIM) + (scb ^ swz);        \
      GLOAD16(ks_, (char*)&Kb[buf][0] + (wave * 16 + i_ * 8) * 128);                \
      const char* vs_ =                                                             \
          (const char*)(Vbase + (size_t)row_ * SEQ + (kv0)) + (scb ^ swz);          \
      GLOAD16(vs_, (char*)&Vb[buf][0] + (wave * 16 + i_ * 8) * 128);                \
    }                                                                               \
  } while (0)

  STAGE(0, 0);
  __syncthreads();

  const int NIT = SEQ / 64;
  for (int it = 0; it < NIT; ++it) {
    const int cur = it & 1;
    if (it + 1 < NIT) STAGE(cur ^ 1, (it + 1) * 64);

    f32x4 s[2][4];
#pragma unroll
    for (int qt = 0; qt < 2; ++qt)
#pragma unroll
      for (int nt = 0; nt < 4; ++nt) s[qt][nt] = f32x4{0.f, 0.f, 0.f, 0.f};
#pragma unroll
    for (int nt = 0; nt < 4; ++nt) {
      const int kr = nt * 16 + r;
#pragma unroll
      for (int ks = 0; ks < 2; ++ks) {
        const bf16x8 kf = *(bf16x8*)((char*)&Kb[cur][0] + kr * 128 +
                                     ((ks * 64 + g * 16) ^ ((kr & 7) << 4)));
        s[0][nt] = MFMA(kf, qf[0][ks], s[0][nt]);
        s[1][nt] = MFMA(kf, qf[1][ks], s[1][nt]);
      }
    }

    float pm[2];
#pragma unroll
    for (int qt = 0; qt < 2; ++qt) {
      f32x4 m4;
#pragma unroll
      for (int i = 0; i < 4; ++i)
        m4[i] = fmaxf(fmaxf(s[qt][0][i], s[qt][1][i]), fmaxf(s[qt][2][i], s[qt][3][i]));
      float t = fmaxf(fmaxf(m4[0], m4[1]), fmaxf(m4[2], m4[3]));
      t = fmaxf(t, __shfl_xor(t, 16));
      t = fmaxf(t, __shfl_xor(t, 32));
      pm[qt] = t;
    }

    const bool need = (pm[0] > m_i[0] + 8.0f) || (pm[1] > m_i[1] + 8.0f);
    if (__any(need)) {
      float alpha[2];
#pragma unroll
      for (int qt = 0; qt < 2; ++qt) {
        const float mn = fmaxf(m_i[qt], pm[qt]);
        alpha[qt] = fast_exp2(m_i[qt] - mn);
        m_i[qt] = mn;
        l_i[qt] *= alpha[qt];
      }
#pragma unroll
      for (int qt = 0; qt < 2; ++qt)
#pragma unroll
        for (int i = 0; i < 4; ++i) {
          const float a = __shfl(alpha[qt], g * 4 + i);
#pragma unroll
          for (int dt = 0; dt < 4; ++dt) accO[qt][dt][i] *= a;
        }
    }

    float rs[2] = {0.f, 0.f};
#pragma unroll
    for (int qt = 0; qt < 2; ++qt) {
      const int row = qt * 16 + r;
      const int rsw = (row & 7) << 4;
#pragma unroll
      for (int nt = 0; nt < 4; ++nt) {
        f32x4 pv;
#pragma unroll
        for (int i = 0; i < 4; ++i) {
          pv[i] = fast_exp2(s[qt][nt][i] - m_i[qt]);
          rs[qt] += pv[i];
        }
        ushort4 pk;
        pk.x = __builtin_bit_cast(unsigned short, (bf16)pv[0]);
        pk.y = __builtin_bit_cast(unsigned short, (bf16)pv[1]);
        pk.z = __builtin_bit_cast(unsigned short, (bf16)pv[2]);
        pk.w = __builtin_bit_cast(unsigned short, (bf16)pv[3]);
        *(ushort4*)((char*)&Pb[wave][0] + row * 128 + ((nt * 32 + g * 8) ^ rsw)) = pk;
      }
      rs[qt] += __shfl_xor(rs[qt], 16);
      rs[qt] += __shfl_xor(rs[qt], 32);
      l_i[qt] += rs[qt];
    }

#pragma unroll
    for (int ss = 0; ss < 2; ++ss) {
      bf16x8 pf[2];
#pragma unroll
      for (int qt = 0; qt < 2; ++qt) {
        const int row = qt * 16 + r;
        pf[qt] = *(bf16x8*)((char*)&Pb[wave][0] + row * 128 +
                            ((ss * 64 + g * 16) ^ ((row & 7) << 4)));
      }
#pragma unroll
      for (int dt = 0; dt < 4; ++dt) {
        const int dr = dt * 16 + r;
        const bf16x8 vf = *(bf16x8*)((char*)&Vb[cur][0] + dr * 128 +
                                     ((ss * 64 + g * 16) ^ ((dr & 7) << 4)));
        accO[0][dt] = MFMA(pf[0], vf, accO[0][dt]);
        accO[1][dt] = MFMA(pf[1], vf, accO[1][dt]);
      }
    }

    __syncthreads();
  }
#undef STAGE

#pragma unroll
  for (int qt = 0; qt < 2; ++qt)
#pragma unroll
    for (int i = 0; i < 4; ++i) {
      const float li = __shfl(l_i[qt], g * 4 + i);
      const float inv = 1.0f / li;
      const int qrow = q0 + qt * 16 + g * 4 + i;
      bf16* cp = ctx + (size_t)(b * SEQ + qrow) * DIM + h * HD;
#pragma unroll
      for (int dt = 0; dt < 4; ++dt)
        cp[dt * 16 + r] = (bf16)(accO[qt][dt][i] * inv);
    }
}

// ---------------------------------------------------------------------------
// Output GEMM: out[m,n] = sum_k ctx[m,k] * Wo[n,k] + bo[n], f32 output.
// Same BK=64 / dbuf / 1-barrier / swizzled structure; both operands GLOAD16.
// ---------------------------------------------------------------------------
__global__ __launch_bounds__(256, 2) void out_gemm(
    const bf16* __restrict__ A, const bf16* __restrict__ W,
    const float* __restrict__ bias, float* __restrict__ out) {
  __shared__ bf16 Ab[2][128 * 64];
  __shared__ bf16 Bb[2][128 * 64];

  const int tid  = threadIdx.x;
  const int wave = tid >> 6, lane = tid & 63;
  const int r = lane & 15, g = lane >> 4;

  const int wg = blockIdx.x;
  const int sw = ((wg & 7) << 6) | (wg >> 3);
  const int m0 = (sw >> 3) * 128, n0 = (sw & 7) * 128;
  const int wm = (wave >> 1) * 64, wn = (wave & 1) * 64;

  f32x4 acc[4][4] = {};

  const int srr = lane >> 3;
  const int scb = (lane & 7) * 16;
  const int swz = srr << 4;

#define STAGE2(buf, k0)                                                             \
  do {                                                                              \
    _Pragma("unroll") for (int i_ = 0; i_ < 4; ++i_) {                              \
      const int row_ = wave * 32 + i_ * 8 + srr;                                    \
      const char* as_ =                                                             \
          (const char*)(A + (size_t)(m0 + row_) * DIM + (k0)) + (scb ^ swz);        \
      GLOAD16(as_, (char*)&Ab[buf][0] + (wave * 32 + i_ * 8) * 128);                \
      const char* bs_ =                                                             \
          (const char*)(W + (size_t)(n0 + row_) * DIM + (k0)) + (scb ^ swz);        \
      GLOAD16(bs_, (char*)&Bb[buf][0] + (wave * 32 + i_ * 8) * 128);                \
    }                                                                               \
  } while (0)

  STAGE2(0, 0);
  __syncthreads();

  const int NK = DIM / 64;
  for (int it = 0; it < NK; ++it) {
    const int cur = it & 1;
    if (it + 1 < NK) STAGE2(cur ^ 1, (it + 1) * 64);

#pragma unroll
    for (int ks = 0; ks < 2; ++ks) {
      bf16x8 af[4], bfr[4];
#pragma unroll
      for (int mt = 0; mt < 4; ++mt) {
        const int mr = wm + mt * 16 + r;
        af[mt] = *(bf16x8*)((char*)&Ab[cur][0] + mr * 128 +
                            ((ks * 64 + g * 16) ^ ((mr & 7) << 4)));
      }
#pragma unroll
      for (int nt = 0; nt < 4; ++nt) {
        const int nr = wn + nt * 16 + r;
        bfr[nt] = *(bf16x8*)((char*)&Bb[cur][0] + nr * 128 +
                             ((ks * 64 + g * 16) ^ ((nr & 7) << 4)));
      }
#pragma unroll
      for (int mt = 0; mt < 4; ++mt)
#pragma unroll
        for (int nt = 0; nt < 4; ++nt)
          acc[mt][nt] = MFMA(af[mt], bfr[nt], acc[mt][nt]);
    }

    __syncthreads();
  }
#undef STAGE2

#pragma unroll
  for (int mt = 0; mt < 4; ++mt)
#pragma unroll
    for (int nt = 0; nt < 4; ++nt) {
      const int n = n0 + wn + nt * 16 + r;
      const float bn = bias[n];
#pragma unroll
      for (int i = 0; i < 4; ++i) {
        const int m = m0 + wm + mt * 16 + g * 4 + i;
        out[(size_t)m * DIM + n] = acc[mt][nt][i] + bn;
      }
    }
}

// ---------------------------------------------------------------------------
// kernel_launch
// ---------------------------------------------------------------------------
extern "C" void kernel_launch(void* const* d_in, const int* in_sizes, int n_in,
                              void* d_out, int out_size, void* d_ws, size_t ws_size,
                              hipStream_t stream) {
  const float* query  = (const float*)d_in[0];
  const float* key_in = (const float*)d_in[1];
  const float* value  = (const float*)d_in[2];
  const float* Wq = (const float*)d_in[3];
  const float* bq = (const float*)d_in[4];
  const float* Wk = (const float*)d_in[5];
  const float* bk = (const float*)d_in[6];
  const float* Wv = (const float*)d_in[7];
  const float* bv = (const float*)d_in[8];
  const float* Wo = (const float*)d_in[9];
  const float* bo = (const float*)d_in[10];

  char* ws = (char*)d_ws;
  const size_t WSZ = (size_t)DIM * DIM * sizeof(bf16);
  const size_t TSZ = (size_t)BATCH * SEQ * DIM * sizeof(bf16);
  bf16* Wq_b = (bf16*)(ws);
  bf16* Wk_b = (bf16*)(ws + WSZ);
  bf16* Wv_b = (bf16*)(ws + 2 * WSZ);
  bf16* Wo_b = (bf16*)(ws + 3 * WSZ);
  bf16* Q_b  = (bf16*)(ws + 4 * WSZ);
  bf16* K_b  = (bf16*)(ws + 4 * WSZ + TSZ);
  bf16* Vt_b = (bf16*)(ws + 4 * WSZ + 2 * TSZ);
  bf16* C_b  = (bf16*)(ws + 4 * WSZ + 3 * TSZ);

  cvt_w_kernel<<<dim3(DIM * DIM / (256 * 4), 4), 256, 0, stream>>>(
      Wq, Wk, Wv, Wo, Wq_b, Wk_b, Wv_b, Wo_b);

  ProjArgs pa;
  pa.A[0] = query; pa.A[1] = key_in; pa.A[2] = value;
  pa.W[0] = Wq_b;  pa.W[1] = Wk_b;   pa.W[2] = Wv_b;
  pa.bias[0] = bq; pa.bias[1] = bk;  pa.bias[2] = bv;
  pa.out[0] = Q_b; pa.out[1] = K_b;  pa.out[2] = Vt_b;
  proj_gemm<<<dim3(512, 1, 3), 256, 0, stream>>>(pa);

  attn_kernel<<<dim3(SEQ / 128, BATCH * NH), 256, 0, stream>>>(Q_b, K_b, Vt_b, C_b);

  out_gemm<<<dim3(512, 1, 1), 256, 0, stream>>>(C_b, Wo_b, bo, (float*)d_out);
}

// Round 4
// 207.099 us; speedup vs baseline: 1.3415x; 1.3415x over previous
//
#include <hip/hip_runtime.h>
#include <hip/hip_bf16.h>
#include <stdint.h>

typedef __bf16 bf16;
typedef __bf16 bf16x8 __attribute__((ext_vector_type(8)));
typedef float f32x4 __attribute__((ext_vector_type(4)));

#define BATCH 4
#define SEQ   2048
#define DIM   1024
#define NH    16
#define HD    64

// Q projection pre-scaled by (1/sqrt(HD)) * log2(e): softmax runs in exp2 domain.
#define QSCALE 0.18033688011112042f  // 0.125 * 1.4426950408889634

#define MFMA(a, b, c) __builtin_amdgcn_mfma_f32_16x16x32_bf16((a), (b), (c), 0, 0, 0)

// global -> LDS direct copy, 16B per lane. LDS dest is wave-uniform base+lane*16.
#define GLOAD16(gsrc, ldst)                                                        \
  __builtin_amdgcn_global_load_lds(                                                \
      (__attribute__((address_space(1))) unsigned int*)(void*)(gsrc),              \
      (__attribute__((address_space(3))) unsigned int*)(ldst), 16, 0, 0)

static __device__ __forceinline__ float fast_exp2(float x) {
#if __has_builtin(__builtin_amdgcn_exp2f)
  return __builtin_amdgcn_exp2f(x);
#else
  return exp2f(x);
#endif
}

// ---------------------------------------------------------------------------
// Weight conversion: f32 -> bf16, 4 tensors of DIM*DIM each.
// ---------------------------------------------------------------------------
__global__ __launch_bounds__(256) void cvt_w_kernel(
    const float* __restrict__ w0, const float* __restrict__ w1,
    const float* __restrict__ w2, const float* __restrict__ w3,
    bf16* __restrict__ o0, bf16* __restrict__ o1,
    bf16* __restrict__ o2, bf16* __restrict__ o3) {
  const float* s;
  bf16* d;
  switch (blockIdx.y) {
    case 0: s = w0; d = o0; break;
    case 1: s = w1; d = o1; break;
    case 2: s = w2; d = o2; break;
    default: s = w3; d = o3; break;
  }
  const int i = (blockIdx.x * 256 + threadIdx.x) * 4;
  const float4 v = *(const float4*)(s + i);
  ushort4 o;
  o.x = __builtin_bit_cast(unsigned short, (bf16)v.x);
  o.y = __builtin_bit_cast(unsigned short, (bf16)v.y);
  o.z = __builtin_bit_cast(unsigned short, (bf16)v.z);
  o.w = __builtin_bit_cast(unsigned short, (bf16)v.w);
  *(ushort4*)((unsigned short*)d + i) = o;
}

// ---------------------------------------------------------------------------
// Projection GEMM: C[m,n] = sum_k A[m,k] * W[n,k] + bias[n]   (nn.Linear)
// A: f32 staged DIRECTLY into LDS via global_load_lds (no VGPR round-trip);
//    f32->bf16 conversion happens in the fragment-read path.
// W: bf16 via global_load_lds.
// Tile 128x128, BK=64, single-buffered (48 KiB LDS -> 3 blocks/CU),
// two barriers per K-step (m97 structure), XCD-chunked block swizzle.
// A rows: 256B, (row&15)<<4 source-side XOR swizzle (16 slots, conflict-free).
// B rows: 128B, (row&7)<<4 swizzle (verified 0 conflicts in R3).
// z=0: out = bf16(C * QSCALE) (Q) | z=1: bf16(C) (K) | z=2: Vt transposed.
// ---------------------------------------------------------------------------
struct ProjArgs {
  const float* A[3];
  const bf16*  W[3];
  const float* bias[3];
  bf16*        out[3];
};

__global__ __launch_bounds__(256, 3) void proj_gemm(ProjArgs p) {
  const int z = blockIdx.z;
  const float* __restrict__ A    = p.A[z];
  const bf16*  __restrict__ W    = p.W[z];
  const float* __restrict__ bias = p.bias[z];
  bf16*        __restrict__ out  = p.out[z];

  __shared__ float Af[128 * 64];  // [row 128][k 64] f32, 256B rows, swizzled
  __shared__ bf16  Bb[128 * 64];  // [row 128][k 64] bf16, 128B rows, swizzled

  const int tid  = threadIdx.x;
  const int wave = tid >> 6, lane = tid & 63;
  const int r = lane & 15, g = lane >> 4;

  // XCD-chunked swizzle: 512 blocks -> each XCD gets 64 contiguous (8m x 8n)
  const int wg = blockIdx.x;
  const int sw = ((wg & 7) << 6) | (wg >> 3);
  const int m0 = (sw >> 3) * 128, n0 = (sw & 7) * 128;
  const int wm = (wave >> 1) * 64, wn = (wave & 1) * 64;

  f32x4 acc[4][4] = {};

  // A staging: 4 rows per gload_lds (16 lanes x 16B per 256B row)
  const int a_sr = lane >> 4;          // sub-row 0..3
  const int a_cb = (lane & 15) * 16;   // byte chunk in row
  // B staging: 8 rows per gload_lds (8 lanes x 16B per 128B row)
  const int b_sr = lane >> 3;
  const int b_cb = (lane & 7) * 16;

  const int NK = DIM / 64;
  for (int it = 0; it < NK; ++it) {
    const int k0 = it * 64;

    // --- stage: all async global->LDS, drained by the barrier ---
#pragma unroll
    for (int i = 0; i < 8; ++i) {
      const int row = wave * 32 + i * 4 + a_sr;
      const char* src = (const char*)(A + (size_t)(m0 + row) * DIM + k0) +
                        (a_cb ^ ((row & 15) << 4));
      GLOAD16(src, (char*)Af + (wave * 32 + i * 4) * 256);
    }
#pragma unroll
    for (int i = 0; i < 4; ++i) {
      const int row = wave * 32 + i * 8 + b_sr;
      const char* src = (const char*)(W + (size_t)(n0 + row) * DIM + k0) +
                        (b_cb ^ ((row & 7) << 4));
      GLOAD16(src, (char*)Bb + (wave * 32 + i * 8) * 128);
    }
    __syncthreads();

    // --- compute: A fragments read as f32 pairs, converted to bf16 ---
#pragma unroll
    for (int ks = 0; ks < 2; ++ks) {
      bf16x8 af[4], bfr[4];
#pragma unroll
      for (int mt = 0; mt < 4; ++mt) {
        const int mr = wm + mt * 16 + r;
        const char* base = (const char*)Af + mr * 256;
        const int asw = (mr & 15) << 4;
        const f32x4 lo = *(const f32x4*)(base + ((ks * 128 + g * 32) ^ asw));
        const f32x4 hi = *(const f32x4*)(base + ((ks * 128 + g * 32 + 16) ^ asw));
        bf16x8 a;
        a[0] = (bf16)lo[0]; a[1] = (bf16)lo[1]; a[2] = (bf16)lo[2]; a[3] = (bf16)lo[3];
        a[4] = (bf16)hi[0]; a[5] = (bf16)hi[1]; a[6] = (bf16)hi[2]; a[7] = (bf16)hi[3];
        af[mt] = a;
      }
#pragma unroll
      for (int nt = 0; nt < 4; ++nt) {
        const int nr = wn + nt * 16 + r;
        bfr[nt] = *(bf16x8*)((char*)Bb + nr * 128 +
                             ((ks * 64 + g * 16) ^ ((nr & 7) << 4)));
      }
#pragma unroll
      for (int mt = 0; mt < 4; ++mt)
#pragma unroll
        for (int nt = 0; nt < 4; ++nt)
          acc[mt][nt] = MFMA(af[mt], bfr[nt], acc[mt][nt]);
    }

    __syncthreads();
  }

  // --- epilogue ---  C/D layout: row = g*4 + i, col = r (per 16x16 tile)
  if (z == 2) {
#pragma unroll
    for (int nt = 0; nt < 4; ++nt) {
      const int n = n0 + wn + nt * 16 + r;
      const float bn = bias[n];
#pragma unroll
      for (int mt = 0; mt < 4; ++mt) {
        const int m = m0 + wm + mt * 16 + g * 4;
        const int b = m >> 11, t = m & 2047;
        ushort4 pk;
        pk.x = __builtin_bit_cast(unsigned short, (bf16)(acc[mt][nt][0] + bn));
        pk.y = __builtin_bit_cast(unsigned short, (bf16)(acc[mt][nt][1] + bn));
        pk.z = __builtin_bit_cast(unsigned short, (bf16)(acc[mt][nt][2] + bn));
        pk.w = __builtin_bit_cast(unsigned short, (bf16)(acc[mt][nt][3] + bn));
        *(ushort4*)((unsigned short*)out + (((size_t)(b * DIM + n)) << 11) + t) = pk;
      }
    }
  } else {
    const float scale = (z == 0) ? QSCALE : 1.0f;
#pragma unroll
    for (int mt = 0; mt < 4; ++mt)
#pragma unroll
      for (int nt = 0; nt < 4; ++nt) {
        const int n = n0 + wn + nt * 16 + r;
        const float bn = bias[n];
#pragma unroll
        for (int i = 0; i < 4; ++i) {
          const int m = m0 + wm + mt * 16 + g * 4 + i;
          out[(size_t)m * DIM + n] = (bf16)((acc[mt][nt][i] + bn) * scale);
        }
      }
  }
}

// ---------------------------------------------------------------------------
// Fused attention, swapped-QK^T structure (unchanged — verified R2/R3).
// ---------------------------------------------------------------------------
__global__ __launch_bounds__(256, 3) void attn_kernel(
    const bf16* __restrict__ Q, const bf16* __restrict__ K,
    const bf16* __restrict__ Vt, bf16* __restrict__ ctx) {
  __shared__ bf16 Kb[2][64 * 64];   // [kv 64][d 64], 128B rows, XOR-swizzled
  __shared__ bf16 Vb[2][64 * 64];   // [d 64][kv 64], 128B rows, XOR-swizzled
  __shared__ bf16 Pb[4][32 * 64];   // per-wave P[q 32][kv 64], XOR-swizzled

  const int tid  = threadIdx.x;
  const int wave = tid >> 6, lane = tid & 63;
  const int r = lane & 15, g = lane >> 4;
  const int bh = blockIdx.y;
  const int b = bh >> 4, h = bh & 15;
  const int q0 = blockIdx.x * 128 + wave * 32;

  bf16x8 qf[2][2];
  {
    const bf16* qp = Q + ((size_t)(b * SEQ + q0 + r) * DIM + h * HD);
#pragma unroll
    for (int qt = 0; qt < 2; ++qt)
#pragma unroll
      for (int ks = 0; ks < 2; ++ks)
        qf[qt][ks] = *(const bf16x8*)(qp + (size_t)qt * 16 * DIM + ks * 32 + g * 8);
  }

  f32x4 accO[2][4] = {};
  float m_i[2] = {-3e38f, -3e38f};
  float l_i[2] = {0.f, 0.f};

  const bf16* Kbase = K + (size_t)(b * SEQ) * DIM + h * HD;
  const bf16* Vbase = Vt + (size_t)(b * DIM + h * HD) * SEQ;

  const int srr = lane >> 3;
  const int scb = (lane & 7) * 16;
  const int swz = srr << 4;

#define STAGE(buf, kv0)                                                             \
  do {                                                                              \
    _Pragma("unroll") for (int i_ = 0; i_ < 2; ++i_) {                              \
      const int row_ = wave * 16 + i_ * 8 + srr;                                    \
      const char* ks_ =                                                             \
          (const char*)(Kbase + (size_t)((kv0) + row_) * DIM) + (scb ^ swz);        \
      GLOAD16(ks_, (char*)&Kb[buf][0] + (wave * 16 + i_ * 8) * 128);                \
      const char* vs_ =                                                             \
          (const char*)(Vbase + (size_t)row_ * SEQ + (kv0)) + (scb ^ swz);          \
      GLOAD16(vs_, (char*)&Vb[buf][0] + (wave * 16 + i_ * 8) * 128);                \
    }                                                                               \
  } while (0)

  STAGE(0, 0);
  __syncthreads();

  const int NIT = SEQ / 64;
  for (int it = 0; it < NIT; ++it) {
    const int cur = it & 1;
    if (it + 1 < NIT) STAGE(cur ^ 1, (it + 1) * 64);

    f32x4 s[2][4];
#pragma unroll
    for (int qt = 0; qt < 2; ++qt)
#pragma unroll
      for (int nt = 0; nt < 4; ++nt) s[qt][nt] = f32x4{0.f, 0.f, 0.f, 0.f};
#pragma unroll
    for (int nt = 0; nt < 4; ++nt) {
      const int kr = nt * 16 + r;
#pragma unroll
      for (int ks = 0; ks < 2; ++ks) {
        const bf16x8 kf = *(bf16x8*)((char*)&Kb[cur][0] + kr * 128 +
                                     ((ks * 64 + g * 16) ^ ((kr & 7) << 4)));
        s[0][nt] = MFMA(kf, qf[0][ks], s[0][nt]);
        s[1][nt] = MFMA(kf, qf[1][ks], s[1][nt]);
      }
    }

    float pm[2];
#pragma unroll
    for (int qt = 0; qt < 2; ++qt) {
      f32x4 m4;
#pragma unroll
      for (int i = 0; i < 4; ++i)
        m4[i] = fmaxf(fmaxf(s[qt][0][i], s[qt][1][i]), fmaxf(s[qt][2][i], s[qt][3][i]));
      float t = fmaxf(fmaxf(m4[0], m4[1]), fmaxf(m4[2], m4[3]));
      t = fmaxf(t, __shfl_xor(t, 16));
      t = fmaxf(t, __shfl_xor(t, 32));
      pm[qt] = t;
    }

    const bool need = (pm[0] > m_i[0] + 8.0f) || (pm[1] > m_i[1] + 8.0f);
    if (__any(need)) {
      float alpha[2];
#pragma unroll
      for (int qt = 0; qt < 2; ++qt) {
        const float mn = fmaxf(m_i[qt], pm[qt]);
        alpha[qt] = fast_exp2(m_i[qt] - mn);
        m_i[qt] = mn;
        l_i[qt] *= alpha[qt];
      }
#pragma unroll
      for (int qt = 0; qt < 2; ++qt)
#pragma unroll
        for (int i = 0; i < 4; ++i) {
          const float a = __shfl(alpha[qt], g * 4 + i);
#pragma unroll
          for (int dt = 0; dt < 4; ++dt) accO[qt][dt][i] *= a;
        }
    }

    float rs[2] = {0.f, 0.f};
#pragma unroll
    for (int qt = 0; qt < 2; ++qt) {
      const int row = qt * 16 + r;
      const int rsw = (row & 7) << 4;
#pragma unroll
      for (int nt = 0; nt < 4; ++nt) {
        f32x4 pv;
#pragma unroll
        for (int i = 0; i < 4; ++i) {
          pv[i] = fast_exp2(s[qt][nt][i] - m_i[qt]);
          rs[qt] += pv[i];
        }
        ushort4 pk;
        pk.x = __builtin_bit_cast(unsigned short, (bf16)pv[0]);
        pk.y = __builtin_bit_cast(unsigned short, (bf16)pv[1]);
        pk.z = __builtin_bit_cast(unsigned short, (bf16)pv[2]);
        pk.w = __builtin_bit_cast(unsigned short, (bf16)pv[3]);
        *(ushort4*)((char*)&Pb[wave][0] + row * 128 + ((nt * 32 + g * 8) ^ rsw)) = pk;
      }
      rs[qt] += __shfl_xor(rs[qt], 16);
      rs[qt] += __shfl_xor(rs[qt], 32);
      l_i[qt] += rs[qt];
    }

#pragma unroll
    for (int ss = 0; ss < 2; ++ss) {
      bf16x8 pf[2];
#pragma unroll
      for (int qt = 0; qt < 2; ++qt) {
        const int row = qt * 16 + r;
        pf[qt] = *(bf16x8*)((char*)&Pb[wave][0] + row * 128 +
                            ((ss * 64 + g * 16) ^ ((row & 7) << 4)));
      }
#pragma unroll
      for (int dt = 0; dt < 4; ++dt) {
        const int dr = dt * 16 + r;
        const bf16x8 vf = *(bf16x8*)((char*)&Vb[cur][0] + dr * 128 +
                                     ((ss * 64 + g * 16) ^ ((dr & 7) << 4)));
        accO[0][dt] = MFMA(pf[0], vf, accO[0][dt]);
        accO[1][dt] = MFMA(pf[1], vf, accO[1][dt]);
      }
    }

    __syncthreads();
  }
#undef STAGE

#pragma unroll
  for (int qt = 0; qt < 2; ++qt)
#pragma unroll
    for (int i = 0; i < 4; ++i) {
      const float li = __shfl(l_i[qt], g * 4 + i);
      const float inv = 1.0f / li;
      const int qrow = q0 + qt * 16 + g * 4 + i;
      bf16* cp = ctx + (size_t)(b * SEQ + qrow) * DIM + h * HD;
#pragma unroll
      for (int dt = 0; dt < 4; ++dt)
        cp[dt * 16 + r] = (bf16)(accO[qt][dt][i] * inv);
    }
}

// ---------------------------------------------------------------------------
// Output GEMM: out[m,n] = sum_k ctx[m,k] * Wo[n,k] + bo[n], f32 output.
// BK=64 / dbuf / 1-barrier / swizzled; both operands GLOAD16. (~16 us in R3.)
// ---------------------------------------------------------------------------
__global__ __launch_bounds__(256, 2) void out_gemm(
    const bf16* __restrict__ A, const bf16* __restrict__ W,
    const float* __restrict__ bias, float* __restrict__ out) {
  __shared__ bf16 Ab[2][128 * 64];
  __shared__ bf16 Bb[2][128 * 64];

  const int tid  = threadIdx.x;
  const int wave = tid >> 6, lane = tid & 63;
  const int r = lane & 15, g = lane >> 4;

  const int wg = blockIdx.x;
  const int sw = ((wg & 7) << 6) | (wg >> 3);
  const int m0 = (sw >> 3) * 128, n0 = (sw & 7) * 128;
  const int wm = (wave >> 1) * 64, wn = (wave & 1) * 64;

  f32x4 acc[4][4] = {};

  const int srr = lane >> 3;
  const int scb = (lane & 7) * 16;
  const int swz = srr << 4;

#define STAGE2(buf, k0)                                                             \
  do {                                                                              \
    _Pragma("unroll") for (int i_ = 0; i_ < 4; ++i_) {                              \
      const int row_ = wave * 32 + i_ * 8 + srr;                                    \
      const char* as_ =                                                             \
          (const char*)(A + (size_t)(m0 + row_) * DIM + (k0)) + (scb ^ swz);        \
      GLOAD16(as_, (char*)&Ab[buf][0] + (wave * 32 + i_ * 8) * 128);                \
      const char* bs_ =                                                             \
          (const char*)(W + (size_t)(n0 + row_) * DIM + (k0)) + (scb ^ swz);        \
      GLOAD16(bs_, (char*)&Bb[buf][0] + (wave * 32 + i_ * 8) * 128);                \
    }                                                                               \
  } while (0)

  STAGE2(0, 0);
  __syncthreads();

  const int NK = DIM / 64;
  for (int it = 0; it < NK; ++it) {
    const int cur = it & 1;
    if (it + 1 < NK) STAGE2(cur ^ 1, (it + 1) * 64);

#pragma unroll
    for (int ks = 0; ks < 2; ++ks) {
      bf16x8 af[4], bfr[4];
#pragma unroll
      for (int mt = 0; mt < 4; ++mt) {
        const int mr = wm + mt * 16 + r;
        af[mt] = *(bf16x8*)((char*)&Ab[cur][0] + mr * 128 +
                            ((ks * 64 + g * 16) ^ ((mr & 7) << 4)));
      }
#pragma unroll
      for (int nt = 0; nt < 4; ++nt) {
        const int nr = wn + nt * 16 + r;
        bfr[nt] = *(bf16x8*)((char*)&Bb[cur][0] + nr * 128 +
                             ((ks * 64 + g * 16) ^ ((nr & 7) << 4)));
      }
#pragma unroll
      for (int mt = 0; mt < 4; ++mt)
#pragma unroll
        for (int nt = 0; nt < 4; ++nt)
          acc[mt][nt] = MFMA(af[mt], bfr[nt], acc[mt][nt]);
    }

    __syncthreads();
  }
#undef STAGE2

#pragma unroll
  for (int mt = 0; mt < 4; ++mt)
#pragma unroll
    for (int nt = 0; nt < 4; ++nt) {
      const int n = n0 + wn + nt * 16 + r;
      const float bn = bias[n];
#pragma unroll
      for (int i = 0; i < 4; ++i) {
        const int m = m0 + wm + mt * 16 + g * 4 + i;
        out[(size_t)m * DIM + n] = acc[mt][nt][i] + bn;
      }
    }
}

// ---------------------------------------------------------------------------
// kernel_launch
// ---------------------------------------------------------------------------
extern "C" void kernel_launch(void* const* d_in, const int* in_sizes, int n_in,
                              void* d_out, int out_size, void* d_ws, size_t ws_size,
                              hipStream_t stream) {
  const float* query  = (const float*)d_in[0];
  const float* key_in = (const float*)d_in[1];
  const float* value  = (const float*)d_in[2];
  const float* Wq = (const float*)d_in[3];
  const float* bq = (const float*)d_in[4];
  const float* Wk = (const float*)d_in[5];
  const float* bk = (const float*)d_in[6];
  const float* Wv = (const float*)d_in[7];
  const float* bv = (const float*)d_in[8];
  const float* Wo = (const float*)d_in[9];
  const float* bo = (const float*)d_in[10];

  char* ws = (char*)d_ws;
  const size_t WSZ = (size_t)DIM * DIM * sizeof(bf16);
  const size_t TSZ = (size_t)BATCH * SEQ * DIM * sizeof(bf16);
  bf16* Wq_b = (bf16*)(ws);
  bf16* Wk_b = (bf16*)(ws + WSZ);
  bf16* Wv_b = (bf16*)(ws + 2 * WSZ);
  bf16* Wo_b = (bf16*)(ws + 3 * WSZ);
  bf16* Q_b  = (bf16*)(ws + 4 * WSZ);
  bf16* K_b  = (bf16*)(ws + 4 * WSZ + TSZ);
  bf16* Vt_b = (bf16*)(ws + 4 * WSZ + 2 * TSZ);
  bf16* C_b  = (bf16*)(ws + 4 * WSZ + 3 * TSZ);

  cvt_w_kernel<<<dim3(DIM * DIM / (256 * 4), 4), 256, 0, stream>>>(
      Wq, Wk, Wv, Wo, Wq_b, Wk_b, Wv_b, Wo_b);

  ProjArgs pa;
  pa.A[0] = query; pa.A[1] = key_in; pa.A[2] = value;
  pa.W[0] = Wq_b;  pa.W[1] = Wk_b;   pa.W[2] = Wv_b;
  pa.bias[0] = bq; pa.bias[1] = bk;  pa.bias[2] = bv;
  pa.out[0] = Q_b; pa.out[1] = K_b;  pa.out[2] = Vt_b;
  proj_gemm<<<dim3(512, 1, 3), 256, 0, stream>>>(pa);

  attn_kernel<<<dim3(SEQ / 128, BATCH * NH), 256, 0, stream>>>(Q_b, K_b, Vt_b, C_b);

  out_gemm<<<dim3(512, 1, 1), 256, 0, stream>>>(C_b, Wo_b, bo, (float*)d_out);
}

// Round 5
// 182.663 us; speedup vs baseline: 1.5210x; 1.1338x over previous
//
#include <hip/hip_runtime.h>
#include <hip/hip_bf16.h>
#include <stdint.h>

typedef __bf16 bf16;
typedef __bf16 bf16x8 __attribute__((ext_vector_type(8)));
typedef float f32x4 __attribute__((ext_vector_type(4)));
typedef float f32x16 __attribute__((ext_vector_type(16)));

#define BATCH 4
#define SEQ   2048
#define DIM   1024
#define NH    16
#define HD    64

// Q projection pre-scaled by (1/sqrt(HD)) * log2(e): softmax runs in exp2 domain.
#define QSCALE 0.18033688011112042f  // 0.125 * 1.4426950408889634

#define MFMA(a, b, c)   __builtin_amdgcn_mfma_f32_16x16x32_bf16((a), (b), (c), 0, 0, 0)
#define MFMA32(a, b, c) __builtin_amdgcn_mfma_f32_32x32x16_bf16((a), (b), (c), 0, 0, 0)

// global -> LDS direct copy, 16B per lane. LDS dest is wave-uniform base+lane*16.
#define GLOAD16(gsrc, ldst)                                                        \
  __builtin_amdgcn_global_load_lds(                                                \
      (__attribute__((address_space(1))) unsigned int*)(void*)(gsrc),              \
      (__attribute__((address_space(3))) unsigned int*)(ldst), 16, 0, 0)

static __device__ __forceinline__ float fast_exp2(float x) {
#if __has_builtin(__builtin_amdgcn_exp2f)
  return __builtin_amdgcn_exp2f(x);
#else
  return exp2f(x);
#endif
}

// ---------------------------------------------------------------------------
// Weight conversion: f32 -> bf16, 4 tensors of DIM*DIM each.
// ---------------------------------------------------------------------------
__global__ __launch_bounds__(256) void cvt_w_kernel(
    const float* __restrict__ w0, const float* __restrict__ w1,
    const float* __restrict__ w2, const float* __restrict__ w3,
    bf16* __restrict__ o0, bf16* __restrict__ o1,
    bf16* __restrict__ o2, bf16* __restrict__ o3) {
  const float* s;
  bf16* d;
  switch (blockIdx.y) {
    case 0: s = w0; d = o0; break;
    case 1: s = w1; d = o1; break;
    case 2: s = w2; d = o2; break;
    default: s = w3; d = o3; break;
  }
  const int i = (blockIdx.x * 256 + threadIdx.x) * 4;
  const float4 v = *(const float4*)(s + i);
  ushort4 o;
  o.x = __builtin_bit_cast(unsigned short, (bf16)v.x);
  o.y = __builtin_bit_cast(unsigned short, (bf16)v.y);
  o.z = __builtin_bit_cast(unsigned short, (bf16)v.z);
  o.w = __builtin_bit_cast(unsigned short, (bf16)v.w);
  *(ushort4*)((unsigned short*)d + i) = o;
}

// ---------------------------------------------------------------------------
// Projection GEMM (unchanged from R4 — 904 TF, at the m97-structure ceiling).
// ---------------------------------------------------------------------------
struct ProjArgs {
  const float* A[3];
  const bf16*  W[3];
  const float* bias[3];
  bf16*        out[3];
};

__global__ __launch_bounds__(256, 3) void proj_gemm(ProjArgs p) {
  const int z = blockIdx.z;
  const float* __restrict__ A    = p.A[z];
  const bf16*  __restrict__ W    = p.W[z];
  const float* __restrict__ bias = p.bias[z];
  bf16*        __restrict__ out  = p.out[z];

  __shared__ float Af[128 * 64];  // [row 128][k 64] f32, 256B rows, swizzled
  __shared__ bf16  Bb[128 * 64];  // [row 128][k 64] bf16, 128B rows, swizzled

  const int tid  = threadIdx.x;
  const int wave = tid >> 6, lane = tid & 63;
  const int r = lane & 15, g = lane >> 4;

  const int wg = blockIdx.x;
  const int sw = ((wg & 7) << 6) | (wg >> 3);
  const int m0 = (sw >> 3) * 128, n0 = (sw & 7) * 128;
  const int wm = (wave >> 1) * 64, wn = (wave & 1) * 64;

  f32x4 acc[4][4] = {};

  const int a_sr = lane >> 4;
  const int a_cb = (lane & 15) * 16;
  const int b_sr = lane >> 3;
  const int b_cb = (lane & 7) * 16;

  const int NK = DIM / 64;
  for (int it = 0; it < NK; ++it) {
    const int k0 = it * 64;

#pragma unroll
    for (int i = 0; i < 8; ++i) {
      const int row = wave * 32 + i * 4 + a_sr;
      const char* src = (const char*)(A + (size_t)(m0 + row) * DIM + k0) +
                        (a_cb ^ ((row & 15) << 4));
      GLOAD16(src, (char*)Af + (wave * 32 + i * 4) * 256);
    }
#pragma unroll
    for (int i = 0; i < 4; ++i) {
      const int row = wave * 32 + i * 8 + b_sr;
      const char* src = (const char*)(W + (size_t)(n0 + row) * DIM + k0) +
                        (b_cb ^ ((row & 7) << 4));
      GLOAD16(src, (char*)Bb + (wave * 32 + i * 8) * 128);
    }
    __syncthreads();

#pragma unroll
    for (int ks = 0; ks < 2; ++ks) {
      bf16x8 af[4], bfr[4];
#pragma unroll
      for (int mt = 0; mt < 4; ++mt) {
        const int mr = wm + mt * 16 + r;
        const char* base = (const char*)Af + mr * 256;
        const int asw = (mr & 15) << 4;
        const f32x4 lo = *(const f32x4*)(base + ((ks * 128 + g * 32) ^ asw));
        const f32x4 hi = *(const f32x4*)(base + ((ks * 128 + g * 32 + 16) ^ asw));
        bf16x8 a;
        a[0] = (bf16)lo[0]; a[1] = (bf16)lo[1]; a[2] = (bf16)lo[2]; a[3] = (bf16)lo[3];
        a[4] = (bf16)hi[0]; a[5] = (bf16)hi[1]; a[6] = (bf16)hi[2]; a[7] = (bf16)hi[3];
        af[mt] = a;
      }
#pragma unroll
      for (int nt = 0; nt < 4; ++nt) {
        const int nr = wn + nt * 16 + r;
        bfr[nt] = *(bf16x8*)((char*)Bb + nr * 128 +
                             ((ks * 64 + g * 16) ^ ((nr & 7) << 4)));
      }
#pragma unroll
      for (int mt = 0; mt < 4; ++mt)
#pragma unroll
        for (int nt = 0; nt < 4; ++nt)
          acc[mt][nt] = MFMA(af[mt], bfr[nt], acc[mt][nt]);
    }

    __syncthreads();
  }

  if (z == 2) {
#pragma unroll
    for (int nt = 0; nt < 4; ++nt) {
      const int n = n0 + wn + nt * 16 + r;
      const float bn = bias[n];
#pragma unroll
      for (int mt = 0; mt < 4; ++mt) {
        const int m = m0 + wm + mt * 16 + g * 4;
        const int b = m >> 11, t = m & 2047;
        ushort4 pk;
        pk.x = __builtin_bit_cast(unsigned short, (bf16)(acc[mt][nt][0] + bn));
        pk.y = __builtin_bit_cast(unsigned short, (bf16)(acc[mt][nt][1] + bn));
        pk.z = __builtin_bit_cast(unsigned short, (bf16)(acc[mt][nt][2] + bn));
        pk.w = __builtin_bit_cast(unsigned short, (bf16)(acc[mt][nt][3] + bn));
        *(ushort4*)((unsigned short*)out + (((size_t)(b * DIM + n)) << 11) + t) = pk;
      }
    }
  } else {
    const float scale = (z == 0) ? QSCALE : 1.0f;
#pragma unroll
    for (int mt = 0; mt < 4; ++mt)
#pragma unroll
      for (int nt = 0; nt < 4; ++nt) {
        const int n = n0 + wn + nt * 16 + r;
        const float bn = bias[n];
#pragma unroll
        for (int i = 0; i < 4; ++i) {
          const int m = m0 + wm + mt * 16 + g * 4 + i;
          out[(size_t)m * DIM + n] = (bf16)((acc[mt][nt][i] + bn) * scale);
        }
      }
  }
}

// ---------------------------------------------------------------------------
// Fused attention, 32x32 swapped structure (m214-style, plain HIP).
// Wave = 32 q-rows (q = lane&31); block = 4 waves = 128 q per (b,h).
// KV tiles of 64, double-buffered LDS (32 KiB total), 1 barrier/iter.
// S^T = mfma_32x32x16(K, Q) x 4 k-steps per 32-kv tile.
// K rows are staged PI-PERMUTED (pi(c)=c^12 for middle 4-blocks) so that
// S^T's C-layout registers line up exactly with PV's B-operand kv order:
// P never leaves registers (16 cvt_pk packs, no LDS, no shuffles).
// O accumulated transposed: O^T = mfma_32x32x16(V^T, P), V^T straight from Vt.
// Online softmax in exp2 domain, per-lane scalars, defer-max THR=8.
// ---------------------------------------------------------------------------
__global__ __launch_bounds__(256, 4) void attn_kernel(
    const bf16* __restrict__ Q, const bf16* __restrict__ K,
    const bf16* __restrict__ Vt, bf16* __restrict__ ctx) {
  __shared__ bf16 Kb[2][64 * 64];   // [kv 64][d 64], 128B rows, XOR-swizzled
  __shared__ bf16 Vb[2][64 * 64];   // [d 64][kv 64], 128B rows, XOR-swizzled

  const int tid  = threadIdx.x;
  const int wave = tid >> 6, lane = tid & 63;
  const int l31 = lane & 31, hi = lane >> 5;

  // XCD-chunked swizzle: 8 heads (x16 q-blocks) per XCD -> KV L2-resident
  const int wg  = blockIdx.x;
  const int swb = (wg & 7) * 128 + (wg >> 3);
  const int qblk = swb & 15, bh = swb >> 4;
  const int b = bh >> 4, h = bh & 15;
  const int q0 = qblk * 128 + wave * 32;

  // Q fragments (B operand): col q = lane&31, k(d) = st*16 + hi*8 + j
  bf16x8 qf[4];
  {
    const bf16* qp = Q + ((size_t)(b * SEQ + q0 + l31) * DIM + h * HD);
#pragma unroll
    for (int st = 0; st < 4; ++st)
      qf[st] = *(const bf16x8*)(qp + st * 16 + hi * 8);
  }

  f32x16 accO[2] = {};        // O^T[d][q]: q = lane&31, d = dt*32 + crow(e,hi)
  float m_i = -3e38f, l_i = 0.0f;

  const bf16* Kbase = K + (size_t)(b * SEQ) * DIM + h * HD;
  const bf16* Vbase = Vt + (size_t)(b * DIM + h * HD) * SEQ;

  const int srr = lane >> 3;        // staged sub-row within 8-row group
  const int scb = (lane & 7) * 16;  // staged byte col
  const int swz = srr << 4;         // == (row&7)<<4 for staged rows

  // K source rows: pi-permuted within each 32-row half (pi(c)=c^12 for
  // middle 4-blocks), so S^T registers land in PV B-operand order.
  int koff[2], voff[2], kdst[2], vdst[2];
#pragma unroll
  for (int i = 0; i < 2; ++i) {
    const int rl = wave * 16 + i * 8 + srr;        // LDS row
    const int r32 = rl & 31;
    const int t = (r32 >> 2) & 3;
    const int rsrc = (rl & 32) + ((t == 1 || t == 2) ? (r32 ^ 12) : r32);
    koff[i] = rsrc * (DIM * 2) + (scb ^ swz);      // byte offset from Kbase
    voff[i] = rl * (SEQ * 2) + (scb ^ swz);        // byte offset from Vbase
    kdst[i] = (wave * 16 + i * 8) * 128;
    vdst[i] = (wave * 16 + i * 8) * 128;
  }

#define STAGE(buf, kv0)                                                             \
  do {                                                                              \
    _Pragma("unroll") for (int i_ = 0; i_ < 2; ++i_) {                              \
      GLOAD16((const char*)Kbase + (size_t)(kv0) * (DIM * 2) + koff[i_],            \
              (char*)&Kb[buf][0] + kdst[i_]);                                       \
      GLOAD16((const char*)Vbase + (size_t)(kv0) * 2 + voff[i_],                    \
              (char*)&Vb[buf][0] + vdst[i_]);                                       \
    }                                                                               \
  } while (0)

  STAGE(0, 0);
  __syncthreads();

  const int NIT = SEQ / 64;
  for (int it = 0; it < NIT; ++it) {
    const int cur = it & 1;
    if (it + 1 < NIT) STAGE(cur ^ 1, (it + 1) * 64);

    // --- S^T = K·Q : 2 kv-tiles x 4 k-steps of mfma_32x32x16 ---
    f32x16 s[2] = {};
    __builtin_amdgcn_s_setprio(1);
#pragma unroll
    for (int kvt = 0; kvt < 2; ++kvt) {
      const int row = kvt * 32 + l31;
      const char* kb = (const char*)&Kb[cur][0] + row * 128;
      const int rsw = (row & 7) << 4;
#pragma unroll
      for (int st = 0; st < 4; ++st) {
        const bf16x8 kf = *(const bf16x8*)(kb + ((st * 32 + hi * 16) ^ rsw));
        s[kvt] = MFMA32(kf, qf[st], s[kvt]);
      }
    }
    __builtin_amdgcn_s_setprio(0);

    // --- row max: 31 lane-local fmax + cross-half merge ---
    float pm = s[0][0];
#pragma unroll
    for (int kvt = 0; kvt < 2; ++kvt)
#pragma unroll
      for (int e = 0; e < 16; ++e)
        if (kvt || e) pm = fmaxf(pm, s[kvt][e]);
    pm = fmaxf(pm, __shfl_xor(pm, 32));

    // --- defer-max: rescale only when running max grew by > 8 (log2) ---
    if (__any(pm > m_i + 8.0f)) {
      const float mn = fmaxf(m_i, pm);
      const float alpha = fast_exp2(m_i - mn);
      m_i = mn;
      l_i *= alpha;
#pragma unroll
      for (int dt = 0; dt < 2; ++dt)
#pragma unroll
        for (int e = 0; e < 16; ++e) accO[dt][e] *= alpha;
    }

    // --- P = exp2(S - m), row-sum ---
    float rs = 0.0f;
#pragma unroll
    for (int kvt = 0; kvt < 2; ++kvt)
#pragma unroll
      for (int e = 0; e < 16; ++e) {
        s[kvt][e] = fast_exp2(s[kvt][e] - m_i);
        rs += s[kvt][e];
      }
    l_i += rs + __shfl_xor(rs, 32);

    // --- pack P to bf16 frags (in-register, thanks to pi-permuted K) ---
    bf16x8 pa[2][2];
#pragma unroll
    for (int kvt = 0; kvt < 2; ++kvt)
#pragma unroll
      for (int kb = 0; kb < 2; ++kb)
#pragma unroll
        for (int j = 0; j < 8; ++j)
          pa[kvt][kb][j] = (bf16)s[kvt][kb * 8 + j];

    // --- O^T += V^T · P ---
    __builtin_amdgcn_s_setprio(1);
#pragma unroll
    for (int dt = 0; dt < 2; ++dt) {
      const int row = dt * 32 + l31;
      const char* vb = (const char*)&Vb[cur][0] + row * 128;
      const int rsw = (row & 7) << 4;
#pragma unroll
      for (int kvt = 0; kvt < 2; ++kvt)
#pragma unroll
        for (int kb = 0; kb < 2; ++kb) {
          const bf16x8 vf =
              *(const bf16x8*)(vb + ((kvt * 64 + kb * 32 + hi * 16) ^ rsw));
          accO[dt] = MFMA32(vf, pa[kvt][kb], accO[dt]);
        }
    }
    __builtin_amdgcn_s_setprio(0);

    __syncthreads();  // drains vmcnt(0): next tile's staging complete
  }
#undef STAGE

  // --- normalize and write ctx: lane owns q = q0+l31, d = dt*32+rr*8+4hi+c ---
  {
    const float inv = 1.0f / l_i;
    bf16* cp = ctx + (size_t)(b * SEQ + q0 + l31) * DIM + h * HD;
#pragma unroll
    for (int dt = 0; dt < 2; ++dt)
#pragma unroll
      for (int rr = 0; rr < 4; ++rr) {
        ushort4 pk;
        pk.x = __builtin_bit_cast(unsigned short, (bf16)(accO[dt][rr * 4 + 0] * inv));
        pk.y = __builtin_bit_cast(unsigned short, (bf16)(accO[dt][rr * 4 + 1] * inv));
        pk.z = __builtin_bit_cast(unsigned short, (bf16)(accO[dt][rr * 4 + 2] * inv));
        pk.w = __builtin_bit_cast(unsigned short, (bf16)(accO[dt][rr * 4 + 3] * inv));
        *(ushort4*)(cp + dt * 32 + rr * 8 + hi * 4) = pk;
      }
  }
}

// ---------------------------------------------------------------------------
// Output GEMM (unchanged from R4 — ~16 us).
// ---------------------------------------------------------------------------
__global__ __launch_bounds__(256, 2) void out_gemm(
    const bf16* __restrict__ A, const bf16* __restrict__ W,
    const float* __restrict__ bias, float* __restrict__ out) {
  __shared__ bf16 Ab[2][128 * 64];
  __shared__ bf16 Bb[2][128 * 64];

  const int tid  = threadIdx.x;
  const int wave = tid >> 6, lane = tid & 63;
  const int r = lane & 15, g = lane >> 4;

  const int wg = blockIdx.x;
  const int sw = ((wg & 7) << 6) | (wg >> 3);
  const int m0 = (sw >> 3) * 128, n0 = (sw & 7) * 128;
  const int wm = (wave >> 1) * 64, wn = (wave & 1) * 64;

  f32x4 acc[4][4] = {};

  const int srr = lane >> 3;
  const int scb = (lane & 7) * 16;
  const int swz = srr << 4;

#define STAGE2(buf, k0)                                                             \
  do {                                                                              \
    _Pragma("unroll") for (int i_ = 0; i_ < 4; ++i_) {                              \
      const int row_ = wave * 32 + i_ * 8 + srr;                                    \
      const char* as_ =                                                             \
          (const char*)(A + (size_t)(m0 + row_) * DIM + (k0)) + (scb ^ swz);        \
      GLOAD16(as_, (char*)&Ab[buf][0] + (wave * 32 + i_ * 8) * 128);                \
      const char* bs_ =                                                             \
          (const char*)(W + (size_t)(n0 + row_) * DIM + (k0)) + (scb ^ swz);        \
      GLOAD16(bs_, (char*)&Bb[buf][0] + (wave * 32 + i_ * 8) * 128);                \
    }                                                                               \
  } while (0)

  STAGE2(0, 0);
  __syncthreads();

  const int NK = DIM / 64;
  for (int it = 0; it < NK; ++it) {
    const int cur = it & 1;
    if (it + 1 < NK) STAGE2(cur ^ 1, (it + 1) * 64);

#pragma unroll
    for (int ks = 0; ks < 2; ++ks) {
      bf16x8 af[4], bfr[4];
#pragma unroll
      for (int mt = 0; mt < 4; ++mt) {
        const int mr = wm + mt * 16 + r;
        af[mt] = *(bf16x8*)((char*)&Ab[cur][0] + mr * 128 +
                            ((ks * 64 + g * 16) ^ ((mr & 7) << 4)));
      }
#pragma unroll
      for (int nt = 0; nt < 4; ++nt) {
        const int nr = wn + nt * 16 + r;
        bfr[nt] = *(bf16x8*)((char*)&Bb[cur][0] + nr * 128 +
                             ((ks * 64 + g * 16) ^ ((nr & 7) << 4)));
      }
#pragma unroll
      for (int mt = 0; mt < 4; ++mt)
#pragma unroll
        for (int nt = 0; nt < 4; ++nt)
          acc[mt][nt] = MFMA(af[mt], bfr[nt], acc[mt][nt]);
    }

    __syncthreads();
  }
#undef STAGE2

#pragma unroll
  for (int mt = 0; mt < 4; ++mt)
#pragma unroll
    for (int nt = 0; nt < 4; ++nt) {
      const int n = n0 + wn + nt * 16 + r;
      const float bn = bias[n];
#pragma unroll
      for (int i = 0; i < 4; ++i) {
        const int m = m0 + wm + mt * 16 + g * 4 + i;
        out[(size_t)m * DIM + n] = acc[mt][nt][i] + bn;
      }
    }
}

// ---------------------------------------------------------------------------
// kernel_launch
// ---------------------------------------------------------------------------
extern "C" void kernel_launch(void* const* d_in, const int* in_sizes, int n_in,
                              void* d_out, int out_size, void* d_ws, size_t ws_size,
                              hipStream_t stream) {
  const float* query  = (const float*)d_in[0];
  const float* key_in = (const float*)d_in[1];
  const float* value  = (const float*)d_in[2];
  const float* Wq = (const float*)d_in[3];
  const float* bq = (const float*)d_in[4];
  const float* Wk = (const float*)d_in[5];
  const float* bk = (const float*)d_in[6];
  const float* Wv = (const float*)d_in[7];
  const float* bv = (const float*)d_in[8];
  const float* Wo = (const float*)d_in[9];
  const float* bo = (const float*)d_in[10];

  char* ws = (char*)d_ws;
  const size_t WSZ = (size_t)DIM * DIM * sizeof(bf16);
  const size_t TSZ = (size_t)BATCH * SEQ * DIM * sizeof(bf16);
  bf16* Wq_b = (bf16*)(ws);
  bf16* Wk_b = (bf16*)(ws + WSZ);
  bf16* Wv_b = (bf16*)(ws + 2 * WSZ);
  bf16* Wo_b = (bf16*)(ws + 3 * WSZ);
  bf16* Q_b  = (bf16*)(ws + 4 * WSZ);
  bf16* K_b  = (bf16*)(ws + 4 * WSZ + TSZ);
  bf16* Vt_b = (bf16*)(ws + 4 * WSZ + 2 * TSZ);
  bf16* C_b  = (bf16*)(ws + 4 * WSZ + 3 * TSZ);

  cvt_w_kernel<<<dim3(DIM * DIM / (256 * 4), 4), 256, 0, stream>>>(
      Wq, Wk, Wv, Wo, Wq_b, Wk_b, Wv_b, Wo_b);

  ProjArgs pa;
  pa.A[0] = query; pa.A[1] = key_in; pa.A[2] = value;
  pa.W[0] = Wq_b;  pa.W[1] = Wk_b;   pa.W[2] = Wv_b;
  pa.bias[0] = bq; pa.bias[1] = bk;  pa.bias[2] = bv;
  pa.out[0] = Q_b; pa.out[1] = K_b;  pa.out[2] = Vt_b;
  proj_gemm<<<dim3(512, 1, 3), 256, 0, stream>>>(pa);

  attn_kernel<<<dim3(1024), 256, 0, stream>>>(Q_b, K_b, Vt_b, C_b);

  out_gemm<<<dim3(512, 1, 1), 256, 0, stream>>>(C_b, Wo_b, bo, (float*)d_out);
}